// Round 1
// baseline (933.401 us; speedup 1.0000x reference)
//
#include <hip/hip_runtime.h>
#include <math.h>

#define MBATCH 8
#define NH 8
#define HID 128
#define SEQ 1024
#define DIN 1024
#define HB (NH * MBATCH)  // 64

// f32 GEMM tile config: 128x128 tile, BK=16, 256 threads, 8x8 per thread
#define BM 128
#define BN 128
#define BK 16
#define TM 8
#define TN 8

// MODE 0: k-projection. C = A@B + bias scattered to head-folded layout
//         [hb][t][d]; also rowdot[hb][t] = sum_d (C_row[d] * wseg[d]).
// MODE 3: q-projection. Same GEMM but only rowdot is written (C skipped).
// MODE 1: batched PV (blockIdx.z = hb). C = A@B, all row-major.
// MODE 2: final projection. A is gathered from head-folded att layout;
//         C = A@B + bias, row-major.
template <int MODE>
__global__ __launch_bounds__(256) void gemm_f32(
    const float* __restrict__ A, const float* __restrict__ B,
    const float* __restrict__ bias, float* __restrict__ C,
    const float* __restrict__ wseg, float* __restrict__ rowdot,
    int M, int N, int K) {
  __shared__ float As[BK][BM + 4];
  __shared__ float Bs[BK][BN + 4];

  const int tid = threadIdx.x;
  const int tx = tid & 15;   // 0..15 col group
  const int ty = tid >> 4;   // 0..15 row group
  const int bm = blockIdx.y * BM;
  const int bn = blockIdx.x * BN;

  if constexpr (MODE == 1) {
    const int z = blockIdx.z;
    A += (size_t)z * M * K;
    B += (size_t)z * K * N;
    C += (size_t)z * M * N;
  }

  float acc[TM][TN];
#pragma unroll
  for (int i = 0; i < TM; i++)
#pragma unroll
    for (int j = 0; j < TN; j++) acc[i][j] = 0.f;

  // A tile: 128 rows x 16 cols = 512 float4; thread does 2 (rows tid>>2, +64)
  const int aRow0 = tid >> 2;
  const int aC4 = tid & 3;
  // B tile: 16 rows x 128 cols = 512 float4; thread does 2 (rows tid>>5, +8)
  const int bRow0 = tid >> 5;
  const int bC4 = tid & 31;

  for (int kt = 0; kt < K; kt += BK) {
// ---- load A tile (transposed into As[k][m]) ----
#pragma unroll
    for (int half = 0; half < 2; ++half) {
      const int r = aRow0 + half * 64;
      const int gr = bm + r;
      const int gk = kt + aC4 * 4;
      float4 v;
      if constexpr (MODE == 2) {
        // gather: A[r=(b,t)][k=(h,d)] = att[((h*MB+b)*SEQ+t)*HID + d]
        const int b = gr >> 10, t = gr & 1023;
        const int h = gk >> 7, d = gk & 127;
        v = *reinterpret_cast<const float4*>(
            A + ((size_t)(h * MBATCH + b) * SEQ + t) * HID + d);
      } else {
        v = *reinterpret_cast<const float4*>(A + (size_t)gr * K + gk);
      }
      As[aC4 * 4 + 0][r] = v.x;
      As[aC4 * 4 + 1][r] = v.y;
      As[aC4 * 4 + 2][r] = v.z;
      As[aC4 * 4 + 3][r] = v.w;
    }
// ---- load B tile ----
#pragma unroll
    for (int half = 0; half < 2; ++half) {
      const int r = bRow0 + half * 8;
      const int gk = kt + r;
      const int gc = bn + bC4 * 4;
      float4 v = *reinterpret_cast<const float4*>(B + (size_t)gk * N + gc);
      *reinterpret_cast<float4*>(&Bs[r][bC4 * 4]) = v;
    }
    __syncthreads();
// ---- inner product ----
#pragma unroll
    for (int k = 0; k < BK; ++k) {
      float fa[TM], fb[TN];
#pragma unroll
      for (int i = 0; i < TM; i++) fa[i] = As[k][ty * TM + i];
#pragma unroll
      for (int j = 0; j < TN; j++) fb[j] = Bs[k][tx * TN + j];
#pragma unroll
      for (int i = 0; i < TM; i++)
#pragma unroll
        for (int j = 0; j < TN; j++)
          acc[i][j] = fmaf(fa[i], fb[j], acc[i][j]);
    }
    __syncthreads();
  }

  // ---- epilogue ----
  if constexpr (MODE == 0 || MODE == 3) {
    // tile spans exactly one head: h = bn >> 7, d = tx*TN + j
    const int h = bn >> 7;
    float wv[TN];
#pragma unroll
    for (int j = 0; j < TN; j++) wv[j] = wseg[tx * TN + j];
#pragma unroll
    for (int i = 0; i < TM; i++) {
      const int r = bm + ty * TM + i;
      const int b = r >> 10, t = r & 1023;
      float vb[TN];
      float p = 0.f;
#pragma unroll
      for (int j = 0; j < TN; j++) {
        vb[j] = acc[i][j] + bias[bn + tx * TN + j];
        p = fmaf(vb[j], wv[j], p);
      }
// reduce p across the 16 tx lanes (contiguous 16-lane groups)
#pragma unroll
      for (int off = 1; off < 16; off <<= 1) p += __shfl_xor(p, off, 16);
      if constexpr (MODE == 0) {
        float* dst =
            C + ((size_t)(h * MBATCH + b) * SEQ + t) * HID + tx * TN;
        float4 v0 = {vb[0], vb[1], vb[2], vb[3]};
        float4 v1 = {vb[4], vb[5], vb[6], vb[7]};
        *reinterpret_cast<float4*>(dst) = v0;
        *reinterpret_cast<float4*>(dst + 4) = v1;
      }
      if (tx == 0) rowdot[(size_t)(h * MBATCH + b) * SEQ + t] = p;
    }
  } else {
#pragma unroll
    for (int i = 0; i < TM; i++) {
      const int r = bm + ty * TM + i;
#pragma unroll
      for (int j = 0; j < TN; j += 4) {
        const int c = bn + tx * TN + j;
        float4 v;
        if constexpr (MODE == 2) {
          v.x = acc[i][j + 0] + bias[c + 0];
          v.y = acc[i][j + 1] + bias[c + 1];
          v.z = acc[i][j + 2] + bias[c + 2];
          v.w = acc[i][j + 3] + bias[c + 3];
        } else {
          v.x = acc[i][j + 0];
          v.y = acc[i][j + 1];
          v.z = acc[i][j + 2];
          v.w = acc[i][j + 3];
        }
        *reinterpret_cast<float4*>(C + (size_t)r * N + c) = v;
      }
    }
  }
}

// score[hb][q][k] = softmax_k( tanh(qs[hb][q] + ks[hb][k]) )
// tanh is bounded -> exp in [e^-1, e^1], no max-subtraction needed.
__global__ __launch_bounds__(256) void score_kernel(
    const float* __restrict__ ksc, const float* __restrict__ qsc,
    float* __restrict__ score) {
  const int rowid = blockIdx.x;  // hb*SEQ + q
  const int hb = rowid >> 10;
  const int tid = threadIdx.x;
  const float qv = qsc[rowid];
  float4 kv =
      *reinterpret_cast<const float4*>(ksc + ((size_t)hb << 10) + tid * 4);
  float e0 = expf(tanhf(qv + kv.x));
  float e1 = expf(tanhf(qv + kv.y));
  float e2 = expf(tanhf(qv + kv.z));
  float e3 = expf(tanhf(qv + kv.w));
  float psum = (e0 + e1) + (e2 + e3);
#pragma unroll
  for (int off = 32; off > 0; off >>= 1) psum += __shfl_down(psum, off);
  __shared__ float s[4];
  if ((tid & 63) == 0) s[tid >> 6] = psum;
  __syncthreads();
  const float inv = 1.0f / ((s[0] + s[1]) + (s[2] + s[3]));
  float4 o = {e0 * inv, e1 * inv, e2 * inv, e3 * inv};
  *reinterpret_cast<float4*>(score + (size_t)rowid * SEQ + tid * 4) = o;
}

extern "C" void kernel_launch(void* const* d_in, const int* in_sizes, int n_in,
                              void* d_out, int out_size, void* d_ws,
                              size_t ws_size, hipStream_t stream) {
  const float* k = (const float*)d_in[0];
  const float* q = (const float*)d_in[1];
  const float* Wk = (const float*)d_in[2];
  const float* bk = (const float*)d_in[3];
  const float* Wq = (const float*)d_in[4];
  const float* bq = (const float*)d_in[5];
  const float* w = (const float*)d_in[6];
  const float* Wp = (const float*)d_in[7];
  const float* bp = (const float*)d_in[8];

  float* out_ptr = (float*)d_out;                        // (8,1024,1024)
  float* score_ptr = out_ptr + (size_t)MBATCH * SEQ * DIN;  // (64,1024,1024)

  float* ws = (float*)d_ws;
  float* kx = ws;                          // 64*1024*128
  float* ks = kx + (size_t)HB * SEQ * HID; // 65536
  float* qs = ks + (size_t)HB * SEQ;       // 65536
  float* att = qs + (size_t)HB * SEQ;      // 64*1024*128

  const dim3 blk(256);
  // k projection -> kx (head-folded, +bias) and ks (dot with w[:128])
  gemm_f32<0><<<dim3(DIN / BN, (MBATCH * SEQ) / BM), blk, 0, stream>>>(
      k, Wk, bk, kx, w, ks, MBATCH * SEQ, DIN, DIN);
  // q projection -> qs only (dot with w[128:])
  gemm_f32<3><<<dim3(DIN / BN, (MBATCH * SEQ) / BM), blk, 0, stream>>>(
      q, Wq, bq, nullptr, w + HID, qs, MBATCH * SEQ, DIN, DIN);
  // softmax(tanh(qs + ks)) -> score output (also output 1 of the tuple)
  score_kernel<<<dim3(HB * SEQ), blk, 0, stream>>>(ks, qs, score_ptr);
  // att[hb] = score[hb] @ kx[hb]   (batched over hb)
  gemm_f32<1><<<dim3(HID / BN, SEQ / BM, HB), blk, 0, stream>>>(
      score_ptr, kx, nullptr, att, nullptr, nullptr, SEQ, HID, SEQ);
  // out = gather(att) @ Wp + bp
  gemm_f32<2><<<dim3(DIN / BN, (MBATCH * SEQ) / BM), blk, 0, stream>>>(
      att, Wp, bp, out_ptr, nullptr, nullptr, MBATCH * SEQ, DIN, DIN);
}

// Round 2
// 257.954 us; speedup vs baseline: 3.6185x; 3.6185x over previous
//
#include <hip/hip_runtime.h>
#include <math.h>

#define MB 8
#define NH 8
#define HID 128
#define SEQ 1024
#define DIN 1024
#define HBN 64  // NH*MB

typedef __bf16 bf16x8 __attribute__((ext_vector_type(8)));
typedef __attribute__((ext_vector_type(4))) float f32x4;
typedef __attribute__((ext_vector_type(8))) unsigned short u16x8;
typedef __attribute__((ext_vector_type(4))) unsigned short u16x4;

__device__ inline unsigned short f2bf(float f) {  // RNE f32->bf16
  unsigned int u = __builtin_bit_cast(unsigned int, f);
  u = (u + 0x7FFFu + ((u >> 16) & 1u)) >> 16;
  return (unsigned short)u;
}

__device__ inline void gload_lds16(const void* g, void* l) {
  __builtin_amdgcn_global_load_lds(
      (const __attribute__((address_space(1))) void*)g,
      (__attribute__((address_space(3))) void*)l, 16, 0, 0);
}

// ---------------- prep kernels ----------------

__global__ __launch_bounds__(256) void cvt_bf16(const float* __restrict__ in,
                                                unsigned short* __restrict__ out) {
  const size_t idx = (size_t)blockIdx.x * 256 + threadIdx.x;  // chunk of 8
  const float4 v0 = *reinterpret_cast<const float4*>(in + idx * 8);
  const float4 v1 = *reinterpret_cast<const float4*>(in + idx * 8 + 4);
  u16x8 p;
  p[0] = f2bf(v0.x); p[1] = f2bf(v0.y); p[2] = f2bf(v0.z); p[3] = f2bf(v0.w);
  p[4] = f2bf(v1.x); p[5] = f2bf(v1.y); p[6] = f2bf(v1.z); p[7] = f2bf(v1.w);
  *reinterpret_cast<u16x8*>(out + idx * 8) = p;
}

// WT[n][k] = bf16(W[k][n]), W is DIN x DIN row-major f32
__global__ __launch_bounds__(256) void transpose_bf16(const float* __restrict__ W,
                                                      unsigned short* __restrict__ WT) {
  __shared__ unsigned short tile[64][65];
  const int bx = blockIdx.x * 64;  // k block
  const int by = blockIdx.y * 64;  // n block
  const int tid = threadIdx.x;
  const int r = tid >> 4;
  const int c4 = tid & 15;
#pragma unroll
  for (int i = 0; i < 4; i++) {
    const int rr = r + i * 16;
    float4 v = *reinterpret_cast<const float4*>(W + (size_t)(bx + rr) * DIN + by + c4 * 4);
    tile[c4 * 4 + 0][rr] = f2bf(v.x);
    tile[c4 * 4 + 1][rr] = f2bf(v.y);
    tile[c4 * 4 + 2][rr] = f2bf(v.z);
    tile[c4 * 4 + 3][rr] = f2bf(v.w);
  }
  __syncthreads();
#pragma unroll
  for (int i = 0; i < 4; i++) {
    const int rr = r + i * 16;
    u16x4 o = {tile[rr][c4 * 4 + 0], tile[rr][c4 * 4 + 1],
               tile[rr][c4 * 4 + 2], tile[rr][c4 * 4 + 3]};
    *reinterpret_cast<u16x4*>(WT + (size_t)(by + rr) * DIN + bx + c4 * 4) = o;
  }
}

// u[din][h] = sum_d Wq[din][h*128+d]*w[128+d]; u[1024*8+h] = sum_d bq[h*128+d]*w[128+d]
__global__ __launch_bounds__(256) void wq_fold(const float* __restrict__ Wq,
                                               const float* __restrict__ bq,
                                               const float* __restrict__ w,
                                               float* __restrict__ u) {
  const int tid = threadIdx.x;
  const int lane = tid & 63;
  const int wv = tid >> 6;
  const int row = blockIdx.x * 4 + wv;  // 0..1027; 1024 == bias row
  if (row > DIN) return;
  const int h = lane >> 3, sub = lane & 7;
  const float* src = (row < DIN) ? (Wq + (size_t)row * DIN) : bq;
  float p = 0.f;
  const int col0 = h * HID + sub * 16;
#pragma unroll
  for (int i = 0; i < 16; i++) p = fmaf(src[col0 + i], w[HID + sub * 16 + i], p);
  p += __shfl_xor(p, 1);
  p += __shfl_xor(p, 2);
  p += __shfl_xor(p, 4);
  if (sub == 0) u[(size_t)row * 8 + h] = p;
}

// qs[(h*MB+b)*SEQ + t] = q[b,t,:] . u[:,h] + c[h]
__global__ __launch_bounds__(256) void qs_kernel(const float* __restrict__ q,
                                                 const float* __restrict__ u,
                                                 float* __restrict__ qs) {
  __shared__ float ul[DIN * 9];
  __shared__ float cs[8];
  const int tid = threadIdx.x;
  for (int idx = tid; idx < DIN * 8; idx += 256)
    ul[(idx >> 3) * 9 + (idx & 7)] = u[idx];
  if (tid < 8) cs[tid] = u[DIN * 8 + tid];
  __syncthreads();
  const int lane = tid & 63, wv = tid >> 6;
  const int m = blockIdx.x * 4 + wv;  // (b,t) row, 0..8191
  const int b = m >> 10, t = m & 1023;
  float a0 = 0, a1 = 0, a2 = 0, a3 = 0, a4 = 0, a5 = 0, a6 = 0, a7 = 0;
  const float* qrow = q + (size_t)m * DIN;
#pragma unroll
  for (int i = 0; i < 16; i++) {
    const int din = lane + i * 64;
    const float v = qrow[din];
    const float* up = ul + din * 9;
    a0 = fmaf(v, up[0], a0); a1 = fmaf(v, up[1], a1);
    a2 = fmaf(v, up[2], a2); a3 = fmaf(v, up[3], a3);
    a4 = fmaf(v, up[4], a4); a5 = fmaf(v, up[5], a5);
    a6 = fmaf(v, up[6], a6); a7 = fmaf(v, up[7], a7);
  }
#pragma unroll
  for (int off = 1; off < 64; off <<= 1) {
    a0 += __shfl_xor(a0, off); a1 += __shfl_xor(a1, off);
    a2 += __shfl_xor(a2, off); a3 += __shfl_xor(a3, off);
    a4 += __shfl_xor(a4, off); a5 += __shfl_xor(a5, off);
    a6 += __shfl_xor(a6, off); a7 += __shfl_xor(a7, off);
  }
  if (lane == 0) {
    qs[((size_t)(0 * MB + b) << 10) + t] = a0 + cs[0];
    qs[((size_t)(1 * MB + b) << 10) + t] = a1 + cs[1];
    qs[((size_t)(2 * MB + b) << 10) + t] = a2 + cs[2];
    qs[((size_t)(3 * MB + b) << 10) + t] = a3 + cs[3];
    qs[((size_t)(4 * MB + b) << 10) + t] = a4 + cs[4];
    qs[((size_t)(5 * MB + b) << 10) + t] = a5 + cs[5];
    qs[((size_t)(6 * MB + b) << 10) + t] = a6 + cs[6];
    qs[((size_t)(7 * MB + b) << 10) + t] = a7 + cs[7];
  }
}

// score[hb][q][k] = softmax_k( tanh(qs[hb][q] + ks[hb][k]) )
__global__ __launch_bounds__(256) void score_kernel(
    const float* __restrict__ ksc, const float* __restrict__ qsc,
    float* __restrict__ score) {
  const int rowid = blockIdx.x;  // hb*SEQ + q
  const int hb = rowid >> 10;
  const int tid = threadIdx.x;
  const float qv = qsc[rowid];
  float4 kv = *reinterpret_cast<const float4*>(ksc + ((size_t)hb << 10) + tid * 4);
  float e0 = expf(tanhf(qv + kv.x));
  float e1 = expf(tanhf(qv + kv.y));
  float e2 = expf(tanhf(qv + kv.z));
  float e3 = expf(tanhf(qv + kv.w));
  float psum = (e0 + e1) + (e2 + e3);
#pragma unroll
  for (int off = 32; off > 0; off >>= 1) psum += __shfl_down(psum, off);
  __shared__ float s[4];
  if ((tid & 63) == 0) s[tid >> 6] = psum;
  __syncthreads();
  const float inv = 1.0f / ((s[0] + s[1]) + (s[2] + s[3]));
  float4 o = {e0 * inv, e1 * inv, e2 * inv, e3 * inv};
  *reinterpret_cast<float4*>(score + (size_t)rowid * SEQ + tid * 4) = o;
}

// ---------------- bf16 MFMA GEMM (m97-style 128x128 tile, BK=32) ----------------
// MODE 0 (KPROJ): A=kb[8192x1024] bf16, BT=WkT, +bias -> kxT[hb][d][t] bf16, ks f32
// MODE 1 (PV):    A=score f32 (reg-staged->bf16), BT=kxT[hb] -> att[hb][q][d] bf16
// MODE 2 (OUT):   A=att gathered bf16, BT=WpT, +bias -> out f32
template <int MODE>
__global__ __launch_bounds__(256) void mfma_gemm(
    const unsigned short* __restrict__ A, const float* __restrict__ Af,
    const unsigned short* __restrict__ BT, const float* __restrict__ bias,
    const float* __restrict__ wseg, unsigned short* __restrict__ Cb,
    float* __restrict__ Cf, float* __restrict__ rowdot, int M, int N, int K) {
  __shared__ __align__(16) unsigned short Alds[128 * 32];
  __shared__ __align__(16) unsigned short Blds[128 * 32];

  const int tid = threadIdx.x;
  const int lane = tid & 63;
  const int wv = tid >> 6;
  const int g = lane >> 4;
  const int c = lane & 15;
  const int bm = blockIdx.y * 128;
  const int bn = blockIdx.x * 128;

  const float* Afp = Af;
  const unsigned short* BTp = BT;
  unsigned short* Cbp = Cb;
  if constexpr (MODE == 1) {
    const int hb = blockIdx.z;
    Afp = Af + (size_t)hb * SEQ * SEQ;
    BTp = BT + (size_t)hb * HID * SEQ;
    Cbp = Cb + (size_t)hb * SEQ * HID;
  }

  f32x4 acc[2][8];
#pragma unroll
  for (int m = 0; m < 2; m++)
#pragma unroll
    for (int n = 0; n < 8; n++) acc[m][n] = (f32x4){0.f, 0.f, 0.f, 0.f};

  for (int kt = 0; kt < K; kt += 32) {
#pragma unroll
    for (int i = 0; i < 2; i++) {
      const int cidx = i * 256 + tid;  // chunk of 8 bf16
      const int row = cidx >> 2;
      const int ko = (cidx & 3) << 3;
      if constexpr (MODE == 0) {
        gload_lds16(A + (size_t)(bm + row) * K + kt + ko, Alds + cidx * 8);
      } else if constexpr (MODE == 2) {
        const int gr = bm + row;
        const int b = gr >> 10, t = gr & 1023;
        const int kk = kt + ko;
        const int h = kk >> 7, d = kk & 127;
        gload_lds16(A + (((size_t)(h * MB + b) * SEQ + t) << 7) + d,
                    Alds + cidx * 8);
      } else {  // PV: f32 score -> bf16 reg-stage
        const float* src = Afp + (size_t)(bm + row) * K + kt + ko;
        const float4 v0 = *reinterpret_cast<const float4*>(src);
        const float4 v1 = *reinterpret_cast<const float4*>(src + 4);
        u16x8 p;
        p[0] = f2bf(v0.x); p[1] = f2bf(v0.y); p[2] = f2bf(v0.z); p[3] = f2bf(v0.w);
        p[4] = f2bf(v1.x); p[5] = f2bf(v1.y); p[6] = f2bf(v1.z); p[7] = f2bf(v1.w);
        *reinterpret_cast<u16x8*>(Alds + cidx * 8) = p;
      }
      gload_lds16(BTp + (size_t)(bn + row) * K + kt + ko, Blds + cidx * 8);
    }
    __syncthreads();

    bf16x8 af[2], bfr[8];
#pragma unroll
    for (int m = 0; m < 2; m++)
      af[m] = *reinterpret_cast<const bf16x8*>(
          Alds + ((wv * 32 + m * 16 + c) * 32 + g * 8));
#pragma unroll
    for (int n = 0; n < 8; n++)
      bfr[n] = *reinterpret_cast<const bf16x8*>(Blds + ((n * 16 + c) * 32 + g * 8));
#pragma unroll
    for (int m = 0; m < 2; m++)
#pragma unroll
      for (int n = 0; n < 8; n++)
        acc[m][n] = __builtin_amdgcn_mfma_f32_16x16x32_bf16(af[m], bfr[n],
                                                            acc[m][n], 0, 0, 0);
    __syncthreads();
  }

  if constexpr (MODE == 0) {
    const int h = bn >> 7;           // tile spans exactly one head
    const int b = bm >> 10;          // tile spans one batch row-block
    const size_t hb = h * MB + b;
    const int tbase = (bm & (SEQ - 1)) + wv * 32;
    float wl[8], bl[8];
#pragma unroll
    for (int n = 0; n < 8; n++) {
      wl[n] = wseg[n * 16 + c];
      bl[n] = bias[bn + n * 16 + c];
    }
#pragma unroll
    for (int m = 0; m < 2; m++) {
      const int t0 = tbase + m * 16 + g * 4;
      float pr0 = 0, pr1 = 0, pr2 = 0, pr3 = 0;
#pragma unroll
      for (int n = 0; n < 8; n++) {
        f32x4 a4 = acc[m][n];
        const float v0 = a4[0] + bl[n], v1 = a4[1] + bl[n];
        const float v2 = a4[2] + bl[n], v3 = a4[3] + bl[n];
        pr0 = fmaf(v0, wl[n], pr0); pr1 = fmaf(v1, wl[n], pr1);
        pr2 = fmaf(v2, wl[n], pr2); pr3 = fmaf(v3, wl[n], pr3);
        u16x4 o = {f2bf(v0), f2bf(v1), f2bf(v2), f2bf(v3)};
        *reinterpret_cast<u16x4*>(Cb + (hb * HID + n * 16 + c) * SEQ + t0) = o;
      }
#pragma unroll
      for (int off = 1; off < 16; off <<= 1) {
        pr0 += __shfl_xor(pr0, off); pr1 += __shfl_xor(pr1, off);
        pr2 += __shfl_xor(pr2, off); pr3 += __shfl_xor(pr3, off);
      }
      if (c == 0) {
        float* rd = rowdot + hb * SEQ + t0;
        rd[0] = pr0; rd[1] = pr1; rd[2] = pr2; rd[3] = pr3;
      }
    }
  } else if constexpr (MODE == 1) {
#pragma unroll
    for (int m = 0; m < 2; m++) {
      const int q0 = bm + wv * 32 + m * 16 + g * 4;
#pragma unroll
      for (int n = 0; n < 8; n++) {
        f32x4 a4 = acc[m][n];
#pragma unroll
        for (int r = 0; r < 4; r++)
          Cbp[(size_t)(q0 + r) * HID + n * 16 + c] = f2bf(a4[r]);
      }
    }
  } else {
#pragma unroll
    for (int m = 0; m < 2; m++) {
      const int r0 = bm + wv * 32 + m * 16 + g * 4;
#pragma unroll
      for (int n = 0; n < 8; n++) {
        f32x4 a4 = acc[m][n];
        const float bb = bias[bn + n * 16 + c];
#pragma unroll
        for (int r = 0; r < 4; r++)
          Cf[(size_t)(r0 + r) * N + bn + n * 16 + c] = a4[r] + bb;
      }
    }
  }
}

extern "C" void kernel_launch(void* const* d_in, const int* in_sizes, int n_in,
                              void* d_out, int out_size, void* d_ws,
                              size_t ws_size, hipStream_t stream) {
  const float* k = (const float*)d_in[0];
  const float* q = (const float*)d_in[1];
  const float* Wk = (const float*)d_in[2];
  const float* bk = (const float*)d_in[3];
  const float* Wq = (const float*)d_in[4];
  const float* bq = (const float*)d_in[5];
  const float* w = (const float*)d_in[6];
  const float* Wp = (const float*)d_in[7];
  const float* bp = (const float*)d_in[8];

  float* out_ptr = (float*)d_out;                           // (8,1024,1024) f32
  float* score_ptr = out_ptr + (size_t)MB * SEQ * DIN;      // (64,1024,1024) f32

  char* wsb = (char*)d_ws;
  unsigned short* kb = (unsigned short*)wsb;                     // 16 MB
  unsigned short* WkT = (unsigned short*)(wsb + 16777216);       // 2 MB
  unsigned short* WpT = (unsigned short*)(wsb + 18874368);       // 2 MB
  unsigned short* kxT = (unsigned short*)(wsb + 20971520);       // 16 MB [hb][d][t]
  unsigned short* att = (unsigned short*)(wsb + 37748736);       // 16 MB [hb][t][d]
  float* ks = (float*)(wsb + 54525952);                          // 256 KB
  float* qs = (float*)(wsb + 54788096);                          // 256 KB
  float* u = (float*)(wsb + 55050240);                           // ~33 KB

  cvt_bf16<<<dim3(4096), dim3(256), 0, stream>>>(k, kb);
  transpose_bf16<<<dim3(16, 16), dim3(256), 0, stream>>>(Wk, WkT);
  transpose_bf16<<<dim3(16, 16), dim3(256), 0, stream>>>(Wp, WpT);
  wq_fold<<<dim3(257), dim3(256), 0, stream>>>(Wq, bq, w, u);
  qs_kernel<<<dim3(2048), dim3(256), 0, stream>>>(q, u, qs);
  // k-projection: kxT + ks
  mfma_gemm<0><<<dim3(8, 64), dim3(256), 0, stream>>>(
      kb, nullptr, WkT, bk, w, kxT, nullptr, ks, MB * SEQ, DIN, DIN);
  // score (output 1)
  score_kernel<<<dim3(HBN * SEQ), dim3(256), 0, stream>>>(ks, qs, score_ptr);
  // att[hb] = score[hb] @ kx[hb]
  mfma_gemm<1><<<dim3(1, 8, HBN), dim3(256), 0, stream>>>(
      nullptr, score_ptr, kxT, nullptr, nullptr, att, nullptr, nullptr,
      SEQ, HID, SEQ);
  // out = gather(att) @ Wp + bp
  mfma_gemm<2><<<dim3(8, 64), dim3(256), 0, stream>>>(
      att, nullptr, WpT, bp, nullptr, nullptr, out_ptr, nullptr,
      MB * SEQ, DIN, DIN);
}

// Round 3
// 200.844 us; speedup vs baseline: 4.6474x; 1.2844x over previous
//
#include <hip/hip_runtime.h>
#include <math.h>

#define MB 8
#define NH 8
#define HID 128
#define SEQ 1024
#define DIN 1024
#define HBN 64  // NH*MB

typedef __bf16 bf16x8 __attribute__((ext_vector_type(8)));
typedef __attribute__((ext_vector_type(4))) float f32x4;
typedef __attribute__((ext_vector_type(8))) unsigned short u16x8;
typedef __attribute__((ext_vector_type(4))) unsigned short u16x4;

__device__ inline unsigned short f2bf(float f) {  // RNE f32->bf16
  unsigned int u = __builtin_bit_cast(unsigned int, f);
  u = (u + 0x7FFFu + ((u >> 16) & 1u)) >> 16;
  return (unsigned short)u;
}

// exp(tanh(x)) via hardware exp2/rcp. Saturates correctly for |x| large.
__device__ inline float fast_expt(float x) {
  float e2 = __builtin_amdgcn_exp2f(x * 2.885390082f);        // e^(2x)
  float t = fmaf(-2.f, __builtin_amdgcn_rcpf(e2 + 1.f), 1.f); // tanh(x)
  return __builtin_amdgcn_exp2f(t * 1.442695041f);            // e^tanh
}

__device__ inline void gload_lds16(const void* g, void* l) {
  __builtin_amdgcn_global_load_lds(
      (const __attribute__((address_space(1))) void*)g,
      (__attribute__((address_space(3))) void*)l, 16, 0, 0);
}

// ---------------- prep kernels ----------------

__global__ __launch_bounds__(256) void cvt_bf16(const float* __restrict__ in,
                                                unsigned short* __restrict__ out) {
  const size_t idx = (size_t)blockIdx.x * 256 + threadIdx.x;  // chunk of 8
  const float4 v0 = *reinterpret_cast<const float4*>(in + idx * 8);
  const float4 v1 = *reinterpret_cast<const float4*>(in + idx * 8 + 4);
  u16x8 p;
  p[0] = f2bf(v0.x); p[1] = f2bf(v0.y); p[2] = f2bf(v0.z); p[3] = f2bf(v0.w);
  p[4] = f2bf(v1.x); p[5] = f2bf(v1.y); p[6] = f2bf(v1.z); p[7] = f2bf(v1.w);
  *reinterpret_cast<u16x8*>(out + idx * 8) = p;
}

// WT[n][k] = bf16(W[k][n]), W is DIN x DIN row-major f32
__global__ __launch_bounds__(256) void transpose_bf16(const float* __restrict__ W,
                                                      unsigned short* __restrict__ WT) {
  __shared__ unsigned short tile[64][65];
  const int bx = blockIdx.x * 64;  // k block
  const int by = blockIdx.y * 64;  // n block
  const int tid = threadIdx.x;
  const int r = tid >> 4;
  const int c4 = tid & 15;
#pragma unroll
  for (int i = 0; i < 4; i++) {
    const int rr = r + i * 16;
    float4 v = *reinterpret_cast<const float4*>(W + (size_t)(bx + rr) * DIN + by + c4 * 4);
    tile[c4 * 4 + 0][rr] = f2bf(v.x);
    tile[c4 * 4 + 1][rr] = f2bf(v.y);
    tile[c4 * 4 + 2][rr] = f2bf(v.z);
    tile[c4 * 4 + 3][rr] = f2bf(v.w);
  }
  __syncthreads();
#pragma unroll
  for (int i = 0; i < 4; i++) {
    const int rr = r + i * 16;
    u16x4 o = {tile[rr][c4 * 4 + 0], tile[rr][c4 * 4 + 1],
               tile[rr][c4 * 4 + 2], tile[rr][c4 * 4 + 3]};
    *reinterpret_cast<u16x4*>(WT + (size_t)(by + rr) * DIN + bx + c4 * 4) = o;
  }
}

// u[din][h] = sum_d Wq[din][h*128+d]*w[128+d]; u[1024*8+h] = bias fold
__global__ __launch_bounds__(256) void wq_fold(const float* __restrict__ Wq,
                                               const float* __restrict__ bq,
                                               const float* __restrict__ w,
                                               float* __restrict__ u) {
  const int tid = threadIdx.x;
  const int lane = tid & 63;
  const int wv = tid >> 6;
  const int row = blockIdx.x * 4 + wv;  // 0..1027; 1024 == bias row
  if (row > DIN) return;
  const int h = lane >> 3, sub = lane & 7;
  const float* src = (row < DIN) ? (Wq + (size_t)row * DIN) : bq;
  float p = 0.f;
  const int col0 = h * HID + sub * 16;
#pragma unroll
  for (int i = 0; i < 16; i++) p = fmaf(src[col0 + i], w[HID + sub * 16 + i], p);
  p += __shfl_xor(p, 1);
  p += __shfl_xor(p, 2);
  p += __shfl_xor(p, 4);
  if (sub == 0) u[(size_t)row * 8 + h] = p;
}

// qs[(h*MB+b)*SEQ + t] = q[b,t,:] . u[:,h] + c[h]
__global__ __launch_bounds__(256) void qs_kernel(const float* __restrict__ q,
                                                 const float* __restrict__ u,
                                                 float* __restrict__ qs) {
  __shared__ float ul[DIN * 9];
  __shared__ float cs[8];
  const int tid = threadIdx.x;
  for (int idx = tid; idx < DIN * 8; idx += 256)
    ul[(idx >> 3) * 9 + (idx & 7)] = u[idx];
  if (tid < 8) cs[tid] = u[DIN * 8 + tid];
  __syncthreads();
  const int lane = tid & 63, wv = tid >> 6;
  const int m = blockIdx.x * 4 + wv;  // (b,t) row, 0..8191
  const int b = m >> 10, t = m & 1023;
  float a0 = 0, a1 = 0, a2 = 0, a3 = 0, a4 = 0, a5 = 0, a6 = 0, a7 = 0;
  const float* qrow = q + (size_t)m * DIN;
#pragma unroll
  for (int i = 0; i < 16; i++) {
    const int din = lane + i * 64;
    const float v = qrow[din];
    const float* up = ul + din * 9;
    a0 = fmaf(v, up[0], a0); a1 = fmaf(v, up[1], a1);
    a2 = fmaf(v, up[2], a2); a3 = fmaf(v, up[3], a3);
    a4 = fmaf(v, up[4], a4); a5 = fmaf(v, up[5], a5);
    a6 = fmaf(v, up[6], a6); a7 = fmaf(v, up[7], a7);
  }
#pragma unroll
  for (int off = 1; off < 64; off <<= 1) {
    a0 += __shfl_xor(a0, off); a1 += __shfl_xor(a1, off);
    a2 += __shfl_xor(a2, off); a3 += __shfl_xor(a3, off);
    a4 += __shfl_xor(a4, off); a5 += __shfl_xor(a5, off);
    a6 += __shfl_xor(a6, off); a7 += __shfl_xor(a7, off);
  }
  if (lane == 0) {
    qs[((size_t)(0 * MB + b) << 10) + t] = a0 + cs[0];
    qs[((size_t)(1 * MB + b) << 10) + t] = a1 + cs[1];
    qs[((size_t)(2 * MB + b) << 10) + t] = a2 + cs[2];
    qs[((size_t)(3 * MB + b) << 10) + t] = a3 + cs[3];
    qs[((size_t)(4 * MB + b) << 10) + t] = a4 + cs[4];
    qs[((size_t)(5 * MB + b) << 10) + t] = a5 + cs[5];
    qs[((size_t)(6 * MB + b) << 10) + t] = a6 + cs[6];
    qs[((size_t)(7 * MB + b) << 10) + t] = a7 + cs[7];
  }
}

// ---------------- bf16 MFMA GEMM (128x128 tile, BK=32) ----------------
// MODE 0 (KPROJ): A=kb bf16, BT=WkT, +bias -> kxT[hb][d][t] bf16, ks f32
// MODE 2 (OUT):   A=att gathered bf16, BT=WpT, +bias -> out f32
template <int MODE>
__global__ __launch_bounds__(256) void mfma_gemm(
    const unsigned short* __restrict__ A, const unsigned short* __restrict__ BT,
    const float* __restrict__ bias, const float* __restrict__ wseg,
    unsigned short* __restrict__ Cb, float* __restrict__ Cf,
    float* __restrict__ rowdot, int M, int N, int K) {
  __shared__ __align__(16) unsigned short Alds[128 * 32];
  __shared__ __align__(16) unsigned short Blds[128 * 32];

  const int tid = threadIdx.x;
  const int lane = tid & 63;
  const int wv = tid >> 6;
  const int g = lane >> 4;
  const int c = lane & 15;
  const int bm = blockIdx.y * 128;
  const int bn = blockIdx.x * 128;

  f32x4 acc[2][8];
#pragma unroll
  for (int m = 0; m < 2; m++)
#pragma unroll
    for (int n = 0; n < 8; n++) acc[m][n] = (f32x4){0.f, 0.f, 0.f, 0.f};

  for (int kt = 0; kt < K; kt += 32) {
#pragma unroll
    for (int i = 0; i < 2; i++) {
      const int cidx = i * 256 + tid;  // chunk of 8 bf16
      const int row = cidx >> 2;
      const int ko = (cidx & 3) << 3;
      if constexpr (MODE == 0) {
        gload_lds16(A + (size_t)(bm + row) * K + kt + ko, Alds + cidx * 8);
      } else {
        const int gr = bm + row;
        const int b = gr >> 10, t = gr & 1023;
        const int kk = kt + ko;
        const int h = kk >> 7, d = kk & 127;
        gload_lds16(A + (((size_t)(h * MB + b) * SEQ + t) << 7) + d,
                    Alds + cidx * 8);
      }
      gload_lds16(BT + (size_t)(bn + row) * K + kt + ko, Blds + cidx * 8);
    }
    __syncthreads();

    bf16x8 af[2], bfr[8];
#pragma unroll
    for (int m = 0; m < 2; m++)
      af[m] = *reinterpret_cast<const bf16x8*>(
          Alds + ((wv * 32 + m * 16 + c) * 32 + g * 8));
#pragma unroll
    for (int n = 0; n < 8; n++)
      bfr[n] = *reinterpret_cast<const bf16x8*>(Blds + ((n * 16 + c) * 32 + g * 8));
#pragma unroll
    for (int m = 0; m < 2; m++)
#pragma unroll
      for (int n = 0; n < 8; n++)
        acc[m][n] = __builtin_amdgcn_mfma_f32_16x16x32_bf16(af[m], bfr[n],
                                                            acc[m][n], 0, 0, 0);
    __syncthreads();
  }

  if constexpr (MODE == 0) {
    const int h = bn >> 7;           // tile spans exactly one head
    const int b = bm >> 10;          // tile spans one batch row-block
    const size_t hb = h * MB + b;
    const int tbase = (bm & (SEQ - 1)) + wv * 32;
    float wl[8], bl[8];
#pragma unroll
    for (int n = 0; n < 8; n++) {
      wl[n] = wseg[n * 16 + c];
      bl[n] = bias[bn + n * 16 + c];
    }
#pragma unroll
    for (int m = 0; m < 2; m++) {
      const int t0 = tbase + m * 16 + g * 4;
      float pr0 = 0, pr1 = 0, pr2 = 0, pr3 = 0;
#pragma unroll
      for (int n = 0; n < 8; n++) {
        f32x4 a4 = acc[m][n];
        const float v0 = a4[0] + bl[n], v1 = a4[1] + bl[n];
        const float v2 = a4[2] + bl[n], v3 = a4[3] + bl[n];
        pr0 = fmaf(v0, wl[n], pr0); pr1 = fmaf(v1, wl[n], pr1);
        pr2 = fmaf(v2, wl[n], pr2); pr3 = fmaf(v3, wl[n], pr3);
        u16x4 o = {f2bf(v0), f2bf(v1), f2bf(v2), f2bf(v3)};
        *reinterpret_cast<u16x4*>(Cb + (hb * HID + n * 16 + c) * SEQ + t0) = o;
      }
#pragma unroll
      for (int off = 1; off < 16; off <<= 1) {
        pr0 += __shfl_xor(pr0, off); pr1 += __shfl_xor(pr1, off);
        pr2 += __shfl_xor(pr2, off); pr3 += __shfl_xor(pr3, off);
      }
      if (c == 0) {
        float* rd = rowdot + hb * SEQ + t0;
        rd[0] = pr0; rd[1] = pr1; rd[2] = pr2; rd[3] = pr3;
      }
    }
  } else {
#pragma unroll
    for (int m = 0; m < 2; m++) {
      const int r0 = bm + wv * 32 + m * 16 + g * 4;
#pragma unroll
      for (int n = 0; n < 8; n++) {
        f32x4 a4 = acc[m][n];
        const float bb = bias[bn + n * 16 + c];
#pragma unroll
        for (int r = 0; r < 4; r++)
          Cf[(size_t)(r0 + r) * N + bn + n * 16 + c] = a4[r] + bb;
      }
    }
  }
}

// ---------------- fused score-gen + PV ----------------
// Per block: hb = blockIdx.y, q-tile bm = blockIdx.x*128.
// Regenerates P = exp(tanh(qs+ks))/rowsum, writes f32 score output,
// feeds bf16 P into MFMA against kxT slab -> att[hb][q][d] bf16.
__global__ __launch_bounds__(256) void pv_fused(
    const unsigned short* __restrict__ kxT,  // [hb][d][t] bf16
    const float* __restrict__ ks, const float* __restrict__ qs,
    float* __restrict__ score, unsigned short* __restrict__ att) {
  __shared__ __align__(16) unsigned short Alds[128 * 32];
  __shared__ __align__(16) unsigned short Blds[128 * 32];
  __shared__ __align__(16) float ksl[SEQ];
  __shared__ __align__(16) float qvl[128];
  __shared__ float invl[128];

  const int tid = threadIdx.x;
  const int hb = blockIdx.y;
  const int bm = blockIdx.x * 128;  // q offset within hb
  const int lane = tid & 63, wv = tid >> 6, g = lane >> 4, c = lane & 15;

  // load ks (full row) and the block's 128 qs values
  for (int i = tid; i < SEQ / 4; i += 256)
    *reinterpret_cast<float4*>(ksl + i * 4) =
        *reinterpret_cast<const float4*>(ks + ((size_t)hb << 10) + i * 4);
  if (tid < 32)
    *reinterpret_cast<float4*>(qvl + tid * 4) = *reinterpret_cast<const float4*>(
        qs + ((size_t)hb << 10) + bm + tid * 4);
  __syncthreads();

  // per-row softmax denominators (2 threads per row)
  {
    const int r = tid >> 1, h = tid & 1;
    const float qv = qvl[r];
    const float* kk = ksl + h * 512;
    float s0 = 0.f, s1 = 0.f;
    for (int i = 0; i < 512; i += 2) {
      s0 += fast_expt(qv + kk[i]);
      s1 += fast_expt(qv + kk[i + 1]);
    }
    float s = s0 + s1;
    s += __shfl_xor(s, 1);
    if (h == 0) invl[r] = __builtin_amdgcn_rcpf(s);
  }
  __syncthreads();

  f32x4 acc[2][8];
#pragma unroll
  for (int m = 0; m < 2; m++)
#pragma unroll
    for (int n = 0; n < 8; n++) acc[m][n] = (f32x4){0.f, 0.f, 0.f, 0.f};

  for (int kt = 0; kt < SEQ; kt += 32) {
// stage kxT slab (B operand)
#pragma unroll
    for (int i = 0; i < 2; i++) {
      const int cidx = i * 256 + tid;
      const int row = cidx >> 2;       // d
      const int ko = (cidx & 3) << 3;  // k offset
      gload_lds16(kxT + ((size_t)hb * HID + row) * SEQ + kt + ko, Blds + cidx * 8);
    }
// generate P slab: normalize, write f32 score, stage bf16 to LDS
#pragma unroll
    for (int i = 0; i < 2; i++) {
      const int cidx = i * 256 + tid;
      const int row = cidx >> 2;       // q row in tile
      const int ko = (cidx & 3) << 3;
      const float qv = qvl[row];
      const float inv = invl[row];
      const float4 k0 = *reinterpret_cast<const float4*>(ksl + kt + ko);
      const float4 k1 = *reinterpret_cast<const float4*>(ksl + kt + ko + 4);
      const float p0 = fast_expt(qv + k0.x) * inv;
      const float p1 = fast_expt(qv + k0.y) * inv;
      const float p2 = fast_expt(qv + k0.z) * inv;
      const float p3 = fast_expt(qv + k0.w) * inv;
      const float p4 = fast_expt(qv + k1.x) * inv;
      const float p5 = fast_expt(qv + k1.y) * inv;
      const float p6 = fast_expt(qv + k1.z) * inv;
      const float p7 = fast_expt(qv + k1.w) * inv;
      float* sp = score + ((size_t)hb << 20) + ((size_t)(bm + row) << 10) + kt + ko;
      const float4 w0 = {p0, p1, p2, p3};
      const float4 w1 = {p4, p5, p6, p7};
      *reinterpret_cast<float4*>(sp) = w0;
      *reinterpret_cast<float4*>(sp + 4) = w1;
      bf16x8 pb;
      pb[0] = (__bf16)p0; pb[1] = (__bf16)p1; pb[2] = (__bf16)p2; pb[3] = (__bf16)p3;
      pb[4] = (__bf16)p4; pb[5] = (__bf16)p5; pb[6] = (__bf16)p6; pb[7] = (__bf16)p7;
      *reinterpret_cast<bf16x8*>(Alds + (size_t)cidx * 8) = pb;
    }
    __syncthreads();

    bf16x8 af[2], bfr[8];
#pragma unroll
    for (int m = 0; m < 2; m++)
      af[m] = *reinterpret_cast<const bf16x8*>(
          Alds + ((wv * 32 + m * 16 + c) * 32 + g * 8));
#pragma unroll
    for (int n = 0; n < 8; n++)
      bfr[n] = *reinterpret_cast<const bf16x8*>(Blds + ((n * 16 + c) * 32 + g * 8));
#pragma unroll
    for (int m = 0; m < 2; m++)
#pragma unroll
      for (int n = 0; n < 8; n++)
        acc[m][n] = __builtin_amdgcn_mfma_f32_16x16x32_bf16(af[m], bfr[n],
                                                            acc[m][n], 0, 0, 0);
    __syncthreads();
  }

// epilogue: att[hb][q][d] bf16
#pragma unroll
  for (int m = 0; m < 2; m++) {
    const int q0 = bm + wv * 32 + m * 16 + g * 4;
#pragma unroll
    for (int n = 0; n < 8; n++) {
      f32x4 a4 = acc[m][n];
#pragma unroll
      for (int r = 0; r < 4; r++)
        att[((size_t)hb * SEQ + q0 + r) * HID + n * 16 + c] = f2bf(a4[r]);
    }
  }
}

extern "C" void kernel_launch(void* const* d_in, const int* in_sizes, int n_in,
                              void* d_out, int out_size, void* d_ws,
                              size_t ws_size, hipStream_t stream) {
  const float* k = (const float*)d_in[0];
  const float* q = (const float*)d_in[1];
  const float* Wk = (const float*)d_in[2];
  const float* bk = (const float*)d_in[3];
  const float* Wq = (const float*)d_in[4];
  const float* bq = (const float*)d_in[5];
  const float* w = (const float*)d_in[6];
  const float* Wp = (const float*)d_in[7];
  const float* bp = (const float*)d_in[8];

  float* out_ptr = (float*)d_out;                       // (8,1024,1024) f32
  float* score_ptr = out_ptr + (size_t)MB * SEQ * DIN;  // (64,1024,1024) f32

  char* wsb = (char*)d_ws;
  unsigned short* kb = (unsigned short*)wsb;                // 16 MB
  unsigned short* WkT = (unsigned short*)(wsb + 16777216);  // 2 MB
  unsigned short* WpT = (unsigned short*)(wsb + 18874368);  // 2 MB
  unsigned short* kxT = (unsigned short*)(wsb + 20971520);  // 16 MB [hb][d][t]
  unsigned short* att = (unsigned short*)(wsb + 37748736);  // 16 MB [hb][t][d]
  float* ks = (float*)(wsb + 54525952);                     // 256 KB
  float* qs = (float*)(wsb + 54788096);                     // 256 KB
  float* u = (float*)(wsb + 55050240);                      // ~33 KB

  cvt_bf16<<<dim3(4096), dim3(256), 0, stream>>>(k, kb);
  transpose_bf16<<<dim3(16, 16), dim3(256), 0, stream>>>(Wk, WkT);
  transpose_bf16<<<dim3(16, 16), dim3(256), 0, stream>>>(Wp, WpT);
  wq_fold<<<dim3(257), dim3(256), 0, stream>>>(Wq, bq, w, u);
  qs_kernel<<<dim3(2048), dim3(256), 0, stream>>>(q, u, qs);
  // k-projection: kxT (bf16, [hb][d][t]) + ks
  mfma_gemm<0><<<dim3(8, 64), dim3(256), 0, stream>>>(
      kb, WkT, bk, w, kxT, nullptr, ks, MB * SEQ, DIN, DIN);
  // fused score generation + write + PV
  pv_fused<<<dim3(8, HBN), dim3(256), 0, stream>>>(kxT, ks, qs, score_ptr, att);
  // out = gather(att) @ Wp + bp
  mfma_gemm<2><<<dim3(8, 64), dim3(256), 0, stream>>>(
      att, WpT, bp, nullptr, nullptr, out_ptr, nullptr, MB * SEQ, DIN, DIN);
}